// Round 5
// baseline (871.885 us; speedup 1.0000x reference)
//
#include <hip/hip_runtime.h>

#define NPATCH   8192
#define PP2      2401
#define CH_STR   50176
#define B_STR    3211264
#define OFF_SC   25690112
#define OFF_COV  45359104
#define OFF_EC   65028096

// ---------------- Threefry-2x32 (bit-exact JAX) ----------------
__device__ __forceinline__ unsigned rotl32(unsigned v, unsigned r){ return (v<<r)|(v>>(32u-r)); }

__device__ __forceinline__ void threefry2x32(unsigned k0, unsigned k1,
                                             unsigned x0, unsigned x1,
                                             unsigned &o0, unsigned &o1){
  unsigned ks2 = k0 ^ k1 ^ 0x1BD11BDAu;
  x0 += k0; x1 += k1;
#define TFR(r) x0 += x1; x1 = rotl32(x1,(r)); x1 ^= x0;
  TFR(13) TFR(15) TFR(26) TFR(6)
  x0 += k1;  x1 += ks2 + 1u;
  TFR(17) TFR(29) TFR(16) TFR(24)
  x0 += ks2; x1 += k0 + 2u;
  TFR(13) TFR(15) TFR(26) TFR(6)
  x0 += k0;  x1 += k1 + 3u;
  TFR(17) TFR(29) TFR(16) TFR(24)
  x0 += k1;  x1 += ks2 + 4u;
  TFR(13) TFR(15) TFR(26) TFR(6)
  x0 += ks2; x1 += k0 + 5u;
#undef TFR
  o0 = x0; o1 = x1;
}

__device__ __forceinline__ float u01f(unsigned b){
  return __uint_as_float((b>>9) | 0x3f800000u) - 1.0f;
}

// ---------------- K1: per-patch Gram, softmax, cov ----------------
// 1 wave per patch, 4 patches per 256-thread block.
__global__ __launch_bounds__(256) void k_stats(const float* __restrict__ x,
                                               float* __restrict__ sc_out,
                                               float* __restrict__ cov_out){
  __shared__ float fmt[4][64*49];               // [wave][c*49+p], stride 49 (odd -> conflict-free)
  __shared__ float mbuf[4][49], mxb[4][49], ivb[4][49];
  const int t = threadIdx.x, w = t>>6, lane = t&63;
  const int n = (blockIdx.x<<2) + w;
  const int b = n>>10, rem = n&1023, hb = rem>>5, wb = rem&31;
  const float* xp = x + b*B_STR + (hb*7)*224 + wb*7;
  float* fm = fmt[w];

  // load patch (49x64) into LDS, transposed as [c][p]
  for (int i=0;i<49;i++){
    int idx = lane + (i<<6);
    int c = idx/49; int p = idx - 49*c; int ph = p/7; int pw = p - 7*ph;
    fm[c*49+p] = xp[c*CH_STR + ph*224 + pw];
  }
  __syncthreads();

  // row means
  if (lane < 49){
    float s = 0.f;
    for (int k=0;k<64;k++) s += fm[k*49+lane];
    mbuf[w][lane] = s * 0.015625f;
  }

  // Gram: lane (ti,tj) owns a 7x7 tile of G
  {
    const int ti = lane/7, tj = lane - 7*(lane/7);
    float acc[7][7];
    if (lane < 49){
      #pragma unroll
      for (int r=0;r<7;r++)
        #pragma unroll
        for (int s=0;s<7;s++) acc[r][s] = 0.f;
      for (int k=0;k<64;k++){
        float av[7], bv[7];
        #pragma unroll
        for (int r=0;r<7;r++) av[r] = fm[k*49 + 7*ti + r];
        #pragma unroll
        for (int s=0;s<7;s++) bv[s] = fm[k*49 + 7*tj + s];
        #pragma unroll
        for (int r=0;r<7;r++)
          #pragma unroll
          for (int s=0;s<7;s++) acc[r][s] = fmaf(av[r], bv[s], acc[r][s]);
      }
    }
    __syncthreads();               // all reads of fm done before overwrite with G
    if (lane < 49){
      #pragma unroll
      for (int r=0;r<7;r++)
        #pragma unroll
        for (int s=0;s<7;s++) fm[(7*ti+r)*49 + 7*tj + s] = acc[r][s];
    }
  }
  __syncthreads();

  // softmax params per row
  if (lane < 49){
    float mx = -3.0e38f;
    for (int q=0;q<49;q++) mx = fmaxf(mx, fm[lane*49+q]);
    float s = 0.f;
    for (int q=0;q<49;q++) s += __expf(fm[lane*49+q]-mx);
    mxb[w][lane] = mx; ivb[w][lane] = 1.f/s;
  }
  __syncthreads();

  // write Sc and cov_big
  float* scp = sc_out + (long)n*PP2;
  float* cvp = cov_out + (long)n*PP2;
  for (int i=lane;i<PP2;i+=64){
    int p = i/49, q = i - 49*p;
    float g = fm[i];
    scp[i] = __expf(g - mxb[w][p]) * ivb[w][p];
    cvp[i] = g*0.015625f - mbuf[w][p]*mbuf[w][q];
  }
}

// ---------------- K1b: deterministic fp64 partial reduction of cov_big ----------------
// 256 blocks, each sums a fixed chunk of 32 patches (fixed 4-way interleaved order).
__global__ __launch_bounds__(256) void k_reduce(const float* __restrict__ cov,
                                                double* __restrict__ part){
  const int c = blockIdx.x;
  const float* base = cov + (long)c*32*PP2;
  for (int i=threadIdx.x; i<PP2; i+=256){
    double a0=0.0,a1=0.0,a2=0.0,a3=0.0;
    #pragma unroll
    for (int n=0;n<32;n+=4){
      a0 += (double)base[(n+0)*PP2+i];
      a1 += (double)base[(n+1)*PP2+i];
      a2 += (double)base[(n+2)*PP2+i];
      a3 += (double)base[(n+3)*PP2+i];
    }
    part[(long)c*PP2+i] = (a0+a1)+(a2+a3);
  }
}

// ---------------- K2: CP-ALS (threefry init + 5 sweeps, fp64) ----------------
__device__ __forceinline__ void gj8_inv(double Aval, int t, double* __restrict__ Vinv){
  // wave 0 only; lane t = i*8+j. Gauss-Jordan without pivoting (V is SPD).
  const int i = t>>3, j = t&7;
  double A = Aval;
  double B = (i==j) ? 1.0 : 0.0;
  #pragma unroll
  for (int k=0;k<8;k++){
    double piv = __shfl(A, k*9, 64);
    double rp  = 1.0 / piv;
    double Akj = __shfl(A, (k<<3)+j, 64);
    double Bkj = __shfl(B, (k<<3)+j, 64);
    double fac = __shfl(A, (i<<3)+k, 64);
    if (i == k){ A *= rp; B *= rp; }
    else { double f = fac*rp; A -= f*Akj; B -= f*Bkj; }
  }
  Vinv[t] = B;
}

__global__ __launch_bounds__(256) void k_als(const double* __restrict__ part,
                                             float* __restrict__ cov_cp){
  __shared__ double Td[PP2];
  __shared__ double f0[8], f1[49*8], f2[49*8], Pb[49*8], tmp[49*8];
  __shared__ double G1[64], G2[64], Vinv[64], Mv[8];
  __shared__ unsigned sw[6];
  const int t = threadIdx.x;

  // combine the 256 fp64 partials in fixed order -> exact-enough global mean
  for (int i=t;i<PP2;i+=256){
    double s = 0.0;
    for (int c=0;c<256;c++) s += part[(long)c*PP2+i];
    Td[i] = s * (1.0/8192.0);
  }

  // ---- JAX partitionable threefry (default since jax 0.4.36) ----
  // split(key(42), 3) foldlike: keys[i] = threefry(0,42, 0, i) -> (o0,o1) pair
  if (t < 3){ unsigned a,b2; threefry2x32(0u,42u,0u,(unsigned)t,a,b2); sw[2*t]=a; sw[2*t+1]=b2; }
  __syncthreads();
  // random_bits(key,32,shape): elem j -> threefry(k0,k1, 0, j), bits = o0 ^ o1
  if (t < 8){ unsigned a,b2; threefry2x32(sw[0],sw[1],0u,(unsigned)t,a,b2);
              f0[t]=(double)u01f(a^b2); }
  for (int i=t;i<392;i+=256){
    unsigned a,b2;
    threefry2x32(sw[2],sw[3],0u,(unsigned)i,a,b2); f1[i]=(double)u01f(a^b2);
    threefry2x32(sw[4],sw[5],0u,(unsigned)i,a,b2); f2[i]=(double)u01f(a^b2);
  }
  __syncthreads();

  for (int it=0; it<5; ++it){
    // ----- mode 0: f0 = mttkrp0 @ pinv(G1*G2) -----
    for (int i=t;i<392;i+=256){                 // Pb = T @ f2
      int p=i>>3, r=i&7; double s=0.0;
      for (int q=0;q<49;q++) s += Td[p*49+q]*f2[(q<<3)+r];
      Pb[i]=s;
    }
    __syncthreads();
    if (t < 64){ int r=t>>3, s2=t&7; double g=0.0;
      for (int p=0;p<49;p++) g += f1[(p<<3)+r]*f1[(p<<3)+s2]; G1[t]=g;
    } else if (t < 128){ int u=t-64, r=u>>3, s2=u&7; double g=0.0;
      for (int q=0;q<49;q++) g += f2[(q<<3)+r]*f2[(q<<3)+s2]; G2[u]=g;
    } else if (t < 136){ int r=t-128; double m=0.0;
      for (int p=0;p<49;p++) m += f1[(p<<3)+r]*Pb[(p<<3)+r]; Mv[r]=m;
    }
    __syncthreads();
    if (t < 64) gj8_inv(G1[t]*G2[t], t, Vinv);
    __syncthreads();
    if (t < 8){ double s=0.0;
      for (int k=0;k<8;k++) s += Mv[k]*Vinv[(k<<3)+t];
      f0[t]=s;
    }
    __syncthreads();
    // ----- mode 1: f1 = (Pb*diag(f0)) @ pinv(f0 f0^T ∘ G2) -----
    if (t < 64){ int r=t>>3, s2=t&7; gj8_inv(f0[r]*f0[s2]*G2[t], t, Vinv); }
    __syncthreads();
    for (int i=t;i<392;i+=256){
      int p=i>>3, r=i&7; double s=0.0;
      #pragma unroll
      for (int k=0;k<8;k++) s += Pb[(p<<3)+k]*f0[k]*Vinv[(k<<3)+r];
      tmp[i]=s;
    }
    __syncthreads();
    for (int i=t;i<392;i+=256) f1[i]=tmp[i];
    __syncthreads();
    // ----- mode 2: f2 = (T@f1 * diag(f0)) @ pinv(f0 f0^T ∘ G1new) -----
    for (int i=t;i<392;i+=256){
      int q=i>>3, r=i&7; double s=0.0;
      for (int p=0;p<49;p++) s += Td[q*49+p]*f1[(p<<3)+r];
      Pb[i]=s;
    }
    __syncthreads();
    if (t < 64){ int r=t>>3, s2=t&7; double g=0.0;
      for (int p=0;p<49;p++) g += f1[(p<<3)+r]*f1[(p<<3)+s2]; G1[t]=g;
    }
    __syncthreads();
    if (t < 64){ int r=t>>3, s2=t&7; gj8_inv(f0[r]*f0[s2]*G1[t], t, Vinv); }
    __syncthreads();
    for (int i=t;i<392;i+=256){
      int q=i>>3, r=i&7; double s=0.0;
      #pragma unroll
      for (int k=0;k<8;k++) s += Pb[(q<<3)+k]*f0[k]*Vinv[(k<<3)+r];
      tmp[i]=s;
    }
    __syncthreads();
    for (int i=t;i<392;i+=256) f2[i]=tmp[i];
    __syncthreads();
  }

  // cov_cp[p][q] = sum_r f1[p][r]*f0[r]*f2[q][r]
  for (int i=t;i<PP2;i+=256){
    int p=i/49, q=i-49*(i/49);
    double s=0.0;
    #pragma unroll
    for (int r=0;r<8;r++) s += f1[(p<<3)+r]*f0[r]*f2[(q<<3)+r];
    cov_cp[i] = (float)s;
  }
}

// ---------------- K3: recompute Gram/softmax, L=Sc+cov_cp, Ec=L@FM, out ----------------
// 1 wave per patch, 3 patches per 192-thread block.
__global__ __launch_bounds__(192) void k_apply(const float* __restrict__ x,
                                               const float* __restrict__ beta_p,
                                               const float* __restrict__ cov_cp,
                                               float* __restrict__ out0,
                                               float* __restrict__ ec_out){
  __shared__ float fmt[3][64*49];
  __shared__ float gbuf[3][PP2];
  __shared__ float mxb[3][49], ivb[3][49];
  const int t = threadIdx.x, w = t>>6, lane = t&63;
  const int n = blockIdx.x*3 + w;
  const bool act = (n < NPATCH);
  const float beta = beta_p[0];
  int b=0, hb=0, wb=0;
  if (act){ b = n>>10; int rem = n&1023; hb = rem>>5; wb = rem&31; }
  const int pbase = b*B_STR + (hb*7)*224 + wb*7;
  float* fm = fmt[w];
  float* G  = gbuf[w];

  if (act){
    for (int i=0;i<49;i++){
      int idx = lane + (i<<6);
      int c = idx/49; int p = idx - 49*c; int ph = p/7; int pw = p - 7*ph;
      fm[c*49+p] = x[pbase + c*CH_STR + ph*224 + pw];
    }
  }
  __syncthreads();

  {
    const int ti = lane/7, tj = lane - 7*(lane/7);
    if (act && lane < 49){
      float acc[7][7];
      #pragma unroll
      for (int r=0;r<7;r++)
        #pragma unroll
        for (int s=0;s<7;s++) acc[r][s] = 0.f;
      for (int k=0;k<64;k++){
        float av[7], bv[7];
        #pragma unroll
        for (int r=0;r<7;r++) av[r] = fm[k*49 + 7*ti + r];
        #pragma unroll
        for (int s=0;s<7;s++) bv[s] = fm[k*49 + 7*tj + s];
        #pragma unroll
        for (int r=0;r<7;r++)
          #pragma unroll
          for (int s=0;s<7;s++) acc[r][s] = fmaf(av[r], bv[s], acc[r][s]);
      }
      #pragma unroll
      for (int r=0;r<7;r++)
        #pragma unroll
        for (int s=0;s<7;s++) G[(7*ti+r)*49 + 7*tj + s] = acc[r][s];
    }
  }
  __syncthreads();

  if (act && lane < 49){
    float mx = -3.0e38f;
    for (int q=0;q<49;q++) mx = fmaxf(mx, G[lane*49+q]);
    float s = 0.f;
    for (int q=0;q<49;q++) s += __expf(G[lane*49+q]-mx);
    mxb[w][lane] = mx; ivb[w][lane] = 1.f/s;
  }
  __syncthreads();

  // in-place: L = softmax(G) + cov_cp
  if (act){
    for (int i=lane;i<PP2;i+=64){
      int p = i/49;
      G[i] = __expf(G[i]-mxb[w][p])*ivb[w][p] + cov_cp[i];
    }
  }
  __syncthreads();

  // PV: lane (ti2,cj) owns a 7(p) x 8(c) tile of Ec
  float a2[7][8];
  const int ti2 = lane>>3, cj = lane&7;
  if (act && lane < 56){
    #pragma unroll
    for (int r=0;r<7;r++)
      #pragma unroll
      for (int s=0;s<8;s++) a2[r][s] = 0.f;
    for (int q=0;q<49;q++){
      float lr[7], fv[8];
      #pragma unroll
      for (int r=0;r<7;r++) lr[r] = G[(7*ti2+r)*49 + q];
      #pragma unroll
      for (int s=0;s<8;s++) fv[s] = fm[((cj<<3)+s)*49 + q];
      #pragma unroll
      for (int r=0;r<7;r++)
        #pragma unroll
        for (int s=0;s<8;s++) a2[r][s] = fmaf(lr[r], fv[s], a2[r][s]);
    }
  }
  __syncthreads();              // all PV reads of fm complete before overwrite
  if (act && lane < 56){
    #pragma unroll
    for (int r=0;r<7;r++)
      #pragma unroll
      for (int s=0;s<8;s++) fm[((cj<<3)+s)*49 + 7*ti2 + r] = a2[r][s];
  }
  __syncthreads();
  if (act){
    for (int i=lane;i<3136;i+=64){
      int c = i/49; int p = i - 49*c; int ph = p/7; int pw = p - 7*ph;
      int adr = pbase + c*CH_STR + ph*224 + pw;
      float ec = fm[i];
      float xv = x[adr];
      ec_out[adr] = ec;
      out0[adr]  = xv * fmaf(beta, ec, xv);
    }
  }
}

extern "C" void kernel_launch(void* const* d_in, const int* in_sizes, int n_in,
                              void* d_out, int out_size, void* d_ws, size_t ws_size,
                              hipStream_t stream){
  (void)in_sizes; (void)n_in; (void)out_size; (void)ws_size;
  const float* x    = (const float*)d_in[0];
  const float* beta = (const float*)d_in[1];
  float* out = (float*)d_out;
  float* sc  = out + OFF_SC;
  float* cov = out + OFF_COV;
  float* ec  = out + OFF_EC;
  // fp64 partials live in the Ec output region (written only by k_apply, later)
  double* part  = (double*)ec;
  float* cov_cp = (float*)d_ws;

  k_stats <<<2048, 256, 0, stream>>>(x, sc, cov);
  k_reduce<<<256,  256, 0, stream>>>(cov, part);
  k_als   <<<1,    256, 0, stream>>>(part, cov_cp);
  k_apply <<<2731, 192, 0, stream>>>(x, beta, cov_cp, out, ec);
}

// Round 7
// 789.897 us; speedup vs baseline: 1.1038x; 1.1038x over previous
//
#include <hip/hip_runtime.h>

#define NPATCH   8192
#define PP2      2401
#define CH_STR   50176
#define B_STR    3211264
#define OFF_SC   25690112
#define OFF_COV  45359104
#define OFF_EC   65028096

// ---------------- Threefry-2x32 (bit-exact JAX partitionable PRNG) ----------------
__device__ __forceinline__ unsigned rotl32(unsigned v, unsigned r){ return (v<<r)|(v>>(32u-r)); }

__device__ __forceinline__ void threefry2x32(unsigned k0, unsigned k1,
                                             unsigned x0, unsigned x1,
                                             unsigned &o0, unsigned &o1){
  unsigned ks2 = k0 ^ k1 ^ 0x1BD11BDAu;
  x0 += k0; x1 += k1;
#define TFR(r) x0 += x1; x1 = rotl32(x1,(r)); x1 ^= x0;
  TFR(13) TFR(15) TFR(26) TFR(6)
  x0 += k1;  x1 += ks2 + 1u;
  TFR(17) TFR(29) TFR(16) TFR(24)
  x0 += ks2; x1 += k0 + 2u;
  TFR(13) TFR(15) TFR(26) TFR(6)
  x0 += k0;  x1 += k1 + 3u;
  TFR(17) TFR(29) TFR(16) TFR(24)
  x0 += k1;  x1 += ks2 + 4u;
  TFR(13) TFR(15) TFR(26) TFR(6)
  x0 += ks2; x1 += k0 + 5u;
#undef TFR
  o0 = x0; o1 = x1;
}

__device__ __forceinline__ float u01f(unsigned b){
  return __uint_as_float((b>>9) | 0x3f800000u) - 1.0f;
}

// ---------------- K1: per-patch Gram, softmax, cov (1 wave per block) ----------------
__global__ __launch_bounds__(64) void k_stats(const float* __restrict__ x,
                                              float* __restrict__ sc_out,
                                              float* __restrict__ cov_out){
  __shared__ float fm[64*49];                   // [c*49+p], stride 49 (odd -> conflict-free)
  __shared__ float mbuf[49], mxb[49], ivb[49];
  const int lane = threadIdx.x;
  const int n = blockIdx.x;
  const int b = n>>10, rem = n&1023, hb = rem>>5, wb = rem&31;
  const float* xp = x + b*B_STR + (hb*7)*224 + wb*7;

  // load patch (49x64) into LDS, transposed as [c][p]
  for (int i=0;i<49;i++){
    int idx = lane + (i<<6);
    int c = idx/49; int p = idx - 49*c; int ph = p/7; int pw = p - 7*ph;
    fm[c*49+p] = xp[c*CH_STR + ph*224 + pw];
  }
  __syncthreads();

  // row means
  if (lane < 49){
    float s = 0.f;
    for (int k=0;k<64;k++) s += fm[k*49+lane];
    mbuf[lane] = s * 0.015625f;
  }

  // Gram: lane (ti,tj) owns a 7x7 tile of G
  {
    const int ti = lane/7, tj = lane - 7*(lane/7);
    float acc[7][7];
    if (lane < 49){
      #pragma unroll
      for (int r=0;r<7;r++)
        #pragma unroll
        for (int s=0;s<7;s++) acc[r][s] = 0.f;
      for (int k=0;k<64;k++){
        float av[7], bv[7];
        #pragma unroll
        for (int r=0;r<7;r++) av[r] = fm[k*49 + 7*ti + r];
        #pragma unroll
        for (int s=0;s<7;s++) bv[s] = fm[k*49 + 7*tj + s];
        #pragma unroll
        for (int r=0;r<7;r++)
          #pragma unroll
          for (int s=0;s<7;s++) acc[r][s] = fmaf(av[r], bv[s], acc[r][s]);
      }
    }
    __syncthreads();               // all reads of fm done before overwrite with G
    if (lane < 49){
      #pragma unroll
      for (int r=0;r<7;r++)
        #pragma unroll
        for (int s=0;s<7;s++) fm[(7*ti+r)*49 + 7*tj + s] = acc[r][s];
    }
  }
  __syncthreads();

  // softmax params per row
  if (lane < 49){
    float mx = -3.0e38f;
    for (int q=0;q<49;q++) mx = fmaxf(mx, fm[lane*49+q]);
    float s = 0.f;
    for (int q=0;q<49;q++) s += __expf(fm[lane*49+q]-mx);
    mxb[lane] = mx; ivb[lane] = 1.f/s;
  }
  __syncthreads();

  // write Sc and cov_big
  float* scp = sc_out + (long)n*PP2;
  float* cvp = cov_out + (long)n*PP2;
  for (int i=lane;i<PP2;i+=64){
    int p = i/49, q = i - 49*p;
    float g = fm[i];
    scp[i] = __expf(g - mxb[p]) * ivb[p];
    cvp[i] = g*0.015625f - mbuf[p]*mbuf[q];
  }
}

// ---------------- K1b: deterministic fp64 partial reduction of cov_big ----------------
// 256 blocks, each sums a fixed chunk of 32 patches (fixed 4-way interleaved order).
__global__ __launch_bounds__(256) void k_reduce(const float* __restrict__ cov,
                                                double* __restrict__ part){
  const int c = blockIdx.x;
  const float* base = cov + (long)c*32*PP2;
  for (int i=threadIdx.x; i<PP2; i+=256){
    double a0=0.0,a1=0.0,a2=0.0,a3=0.0;
    #pragma unroll
    for (int n=0;n<32;n+=4){
      a0 += (double)base[(n+0)*PP2+i];
      a1 += (double)base[(n+1)*PP2+i];
      a2 += (double)base[(n+2)*PP2+i];
      a3 += (double)base[(n+3)*PP2+i];
    }
    part[(long)c*PP2+i] = (a0+a1)+(a2+a3);
  }
}

// ---------------- K1c: combine 256 partials (parallel; same ascending-c order) ----------
__global__ __launch_bounds__(256) void k_reduce2(const double* __restrict__ part,
                                                 double* __restrict__ td){
  const int i = blockIdx.x*256 + threadIdx.x;
  if (i < PP2){
    double s = 0.0;
    for (int c=0;c<256;c++) s += part[(long)c*PP2+i];
    td[i] = s * (1.0/8192.0);
  }
}

// ---------------- K2: CP-ALS (threefry init + 5 sweeps, fp64) ----------------
__device__ __forceinline__ void gj8_inv(double Aval, int t, double* __restrict__ Vinv){
  // wave 0 only; lane t = i*8+j. Gauss-Jordan without pivoting (V is SPD).
  const int i = t>>3, j = t&7;
  double A = Aval;
  double B = (i==j) ? 1.0 : 0.0;
  #pragma unroll
  for (int k=0;k<8;k++){
    double piv = __shfl(A, k*9, 64);
    double rp  = 1.0 / piv;
    double Akj = __shfl(A, (k<<3)+j, 64);
    double Bkj = __shfl(B, (k<<3)+j, 64);
    double fac = __shfl(A, (i<<3)+k, 64);
    if (i == k){ A *= rp; B *= rp; }
    else { double f = fac*rp; A -= f*Akj; B -= f*Bkj; }
  }
  Vinv[t] = B;
}

__global__ __launch_bounds__(256) void k_als(const double* __restrict__ td_g,
                                             float* __restrict__ cov_cp){
  __shared__ double Td[PP2];
  __shared__ double f0[8], f1[49*8], f2[49*8], Pb[49*8], tmp[49*8];
  __shared__ double G1[64], G2[64], Vinv[64], Mv[8];
  __shared__ unsigned sw[6];
  const int t = threadIdx.x;

  for (int i=t;i<PP2;i+=256) Td[i] = td_g[i];

  // ---- JAX partitionable threefry (default since jax 0.4.36) ----
  // split(key(42), 3) foldlike: keys[i] = threefry(0,42, 0, i) -> (o0,o1) pair
  if (t < 3){ unsigned a,b2; threefry2x32(0u,42u,0u,(unsigned)t,a,b2); sw[2*t]=a; sw[2*t+1]=b2; }
  __syncthreads();
  // random_bits(key,32,shape): elem j -> threefry(k0,k1, 0, j), bits = o0 ^ o1
  if (t < 8){ unsigned a,b2; threefry2x32(sw[0],sw[1],0u,(unsigned)t,a,b2);
              f0[t]=(double)u01f(a^b2); }
  for (int i=t;i<392;i+=256){
    unsigned a,b2;
    threefry2x32(sw[2],sw[3],0u,(unsigned)i,a,b2); f1[i]=(double)u01f(a^b2);
    threefry2x32(sw[4],sw[5],0u,(unsigned)i,a,b2); f2[i]=(double)u01f(a^b2);
  }
  __syncthreads();

  for (int it=0; it<5; ++it){
    // ----- mode 0: f0 = mttkrp0 @ pinv(G1*G2) -----
    for (int i=t;i<392;i+=256){                 // Pb = T @ f2
      int p=i>>3, r=i&7; double s=0.0;
      for (int q=0;q<49;q++) s += Td[p*49+q]*f2[(q<<3)+r];
      Pb[i]=s;
    }
    __syncthreads();
    if (t < 64){ int r=t>>3, s2=t&7; double g=0.0;
      for (int p=0;p<49;p++) g += f1[(p<<3)+r]*f1[(p<<3)+s2]; G1[t]=g;
    } else if (t < 128){ int u=t-64, r=u>>3, s2=u&7; double g=0.0;
      for (int q=0;q<49;q++) g += f2[(q<<3)+r]*f2[(q<<3)+s2]; G2[u]=g;
    } else if (t < 136){ int r=t-128; double m=0.0;
      for (int p=0;p<49;p++) m += f1[(p<<3)+r]*Pb[(p<<3)+r]; Mv[r]=m;
    }
    __syncthreads();
    if (t < 64) gj8_inv(G1[t]*G2[t], t, Vinv);
    __syncthreads();
    if (t < 8){ double s=0.0;
      for (int k=0;k<8;k++) s += Mv[k]*Vinv[(k<<3)+t];
      f0[t]=s;
    }
    __syncthreads();
    // ----- mode 1: f1 = (Pb*diag(f0)) @ pinv(f0 f0^T ∘ G2) -----
    if (t < 64){ int r=t>>3, s2=t&7; gj8_inv(f0[r]*f0[s2]*G2[t], t, Vinv); }
    __syncthreads();
    for (int i=t;i<392;i+=256){
      int p=i>>3, r=i&7; double s=0.0;
      #pragma unroll
      for (int k=0;k<8;k++) s += Pb[(p<<3)+k]*f0[k]*Vinv[(k<<3)+r];
      tmp[i]=s;
    }
    __syncthreads();
    for (int i=t;i<392;i+=256) f1[i]=tmp[i];
    __syncthreads();
    // ----- mode 2: f2 = (T@f1 * diag(f0)) @ pinv(f0 f0^T ∘ G1new) -----
    for (int i=t;i<392;i+=256){
      int q=i>>3, r=i&7; double s=0.0;
      for (int p=0;p<49;p++) s += Td[q*49+p]*f1[(p<<3)+r];
      Pb[i]=s;
    }
    __syncthreads();
    if (t < 64){ int r=t>>3, s2=t&7; double g=0.0;
      for (int p=0;p<49;p++) g += f1[(p<<3)+r]*f1[(p<<3)+s2]; G1[t]=g;
    }
    __syncthreads();
    if (t < 64){ int r=t>>3, s2=t&7; gj8_inv(f0[r]*f0[s2]*G1[t], t, Vinv); }
    __syncthreads();
    for (int i=t;i<392;i+=256){
      int q=i>>3, r=i&7; double s=0.0;
      #pragma unroll
      for (int k=0;k<8;k++) s += Pb[(q<<3)+k]*f0[k]*Vinv[(k<<3)+r];
      tmp[i]=s;
    }
    __syncthreads();
    for (int i=t;i<392;i+=256) f2[i]=tmp[i];
    __syncthreads();
  }

  // cov_cp[p][q] = sum_r f1[p][r]*f0[r]*f2[q][r]
  for (int i=t;i<PP2;i+=256){
    int p=i/49, q=i-49*(i/49);
    double s=0.0;
    #pragma unroll
    for (int r=0;r<8;r++) s += f1[(p<<3)+r]*f0[r]*f2[(q<<3)+r];
    cov_cp[i] = (float)s;
  }
}

// ---------------- K3: L = Sc(read) + cov_cp, Ec = L@FM, out (1 wave per block) --------
__global__ __launch_bounds__(64) void k_apply(const float* __restrict__ x,
                                              const float* __restrict__ beta_p,
                                              const float* __restrict__ cov_cp,
                                              const float* __restrict__ sc_in,
                                              float* __restrict__ out0,
                                              float* __restrict__ ec_out){
  __shared__ float fm[64*49];     // x patch [c*49+p]; later overwritten with Ec
  __shared__ float G[PP2];        // L = Sc + cov_cp
  const int lane = threadIdx.x;
  const int n = blockIdx.x;
  const float beta = beta_p[0];
  const int b = n>>10, rem = n&1023, hb = rem>>5, wb = rem&31;
  const int pbase = b*B_STR + (hb*7)*224 + wb*7;
  const float* scp = sc_in + (long)n*PP2;

  // load patch (49x64) into LDS, transposed as [c][p]
  for (int i=0;i<49;i++){
    int idx = lane + (i<<6);
    int c = idx/49; int p = idx - 49*c; int ph = p/7; int pw = p - 7*ph;
    fm[c*49+p] = x[pbase + c*CH_STR + ph*224 + pw];
  }
  // L = Sc + cov_cp  (Sc bits identical to what k_stats wrote; cov_cp is L2-resident)
  for (int i=lane;i<PP2;i+=64) G[i] = scp[i] + cov_cp[i];
  __syncthreads();

  // save this lane's x values before fm is overwritten with Ec (static indexing)
  float xsave[49];
  #pragma unroll
  for (int j=0;j<49;j++) xsave[j] = fm[lane + (j<<6)];

  // PV: lane (ti2,cj) owns a 7(p) x 8(c) tile of Ec
  float a2[7][8];
  const int ti2 = lane>>3, cj = lane&7;
  if (lane < 56){
    #pragma unroll
    for (int r=0;r<7;r++)
      #pragma unroll
      for (int s=0;s<8;s++) a2[r][s] = 0.f;
    for (int q=0;q<49;q++){
      float lr[7], fv[8];
      #pragma unroll
      for (int r=0;r<7;r++) lr[r] = G[(7*ti2+r)*49 + q];
      #pragma unroll
      for (int s=0;s<8;s++) fv[s] = fm[((cj<<3)+s)*49 + q];
      #pragma unroll
      for (int r=0;r<7;r++)
        #pragma unroll
        for (int s=0;s<8;s++) a2[r][s] = fmaf(lr[r], fv[s], a2[r][s]);
    }
  }
  __syncthreads();              // all PV/xsave reads of fm complete before overwrite
  if (lane < 56){
    #pragma unroll
    for (int r=0;r<7;r++)
      #pragma unroll
      for (int s=0;s<8;s++) fm[((cj<<3)+s)*49 + 7*ti2 + r] = a2[r][s];
  }
  __syncthreads();
  #pragma unroll
  for (int j=0;j<49;j++){
    int i = lane + (j<<6);
    int c = i/49; int p = i - 49*c; int ph = p/7; int pw = p - 7*ph;
    int adr = pbase + c*CH_STR + ph*224 + pw;
    float ec = fm[i];
    float xv = xsave[j];
    ec_out[adr] = ec;
    out0[adr]  = xv * fmaf(beta, ec, xv);
  }
}

extern "C" void kernel_launch(void* const* d_in, const int* in_sizes, int n_in,
                              void* d_out, int out_size, void* d_ws, size_t ws_size,
                              hipStream_t stream){
  (void)in_sizes; (void)n_in; (void)out_size; (void)ws_size;
  const float* x    = (const float*)d_in[0];
  const float* beta = (const float*)d_in[1];
  float* out = (float*)d_out;
  float* sc  = out + OFF_SC;
  float* cov = out + OFF_COV;
  float* ec  = out + OFF_EC;
  // fp64 partials live in the Ec output region (written only by k_apply, later)
  double* part  = (double*)ec;
  double* td    = (double*)d_ws;          // 2401 fp64
  float* cov_cp = (float*)(td + 2432);    // 2401 fp32

  k_stats  <<<8192, 64,  0, stream>>>(x, sc, cov);
  k_reduce <<<256,  256, 0, stream>>>(cov, part);
  k_reduce2<<<10,   256, 0, stream>>>(part, td);
  k_als    <<<1,    256, 0, stream>>>(td, cov_cp);
  k_apply  <<<8192, 64,  0, stream>>>(x, beta, cov_cp, sc, out, ec);
}